// Round 8
// baseline (433.061 us; speedup 1.0000x reference)
//
#include <hip/hip_runtime.h>
#include <hip/hip_bf16.h>

#define BATCH 2048
#define IN_DIM 128
#define GRIDN 128
#define HID 256
#define DEPTH 7

typedef unsigned int u32;
typedef __attribute__((ext_vector_type(8))) short short8;
typedef __attribute__((ext_vector_type(4))) float floatx4;

// ---------------- ws layout (bytes) ----------------
// fs2: bf16, MFMA-frag-ordered: [slab:896][nhalf:2][ks:4][tt:8][l4:4][l15:16][g8:8]
#define OFF_FST   ((size_t)0)
#define SZ_FST    ((size_t)7*128*256*128*2)       // 58,720,256
#define OFF_ZT    (OFF_FST + SZ_FST)              // fp32 z_t [128][2048]
#define SZ_ZT     ((size_t)BATCH*IN_DIM*4)
#define OFF_HPRE  (OFF_ZT + SZ_ZT)                // fp32 h_pre [2048][256]
#define SZ_HPRE   ((size_t)BATCH*HID*4)
#define OFF_STATS (OFF_HPRE + SZ_HPRE)            // fp32 stats 3*[512]
#define SZ_STATS  ((size_t)3*2*HID*4)
#define OFF_KEYS  (OFF_STATS + SZ_STATS)          // u32 keys [256]
#define SZ_KEYS   ((size_t)256*4)
#define OFF_CW    (OFF_KEYS + SZ_KEYS)            // fp32 cw[7] (+pad)
#define SZ_CW     ((size_t)32)
#define OFF_Y1    (OFF_CW + SZ_CW)
#define SZ_Y      ((size_t)BATCH*HID*4)
#define OFF_Y2    (OFF_Y1 + SZ_Y)
#define OFF_Y3    (OFF_Y2 + SZ_Y)

#define FENCE __asm__ volatile("" ::: "memory")
#define WAITV(c) do { __builtin_amdgcn_s_waitcnt(c); FENCE; } while (0)
#define BARR do { FENCE; __builtin_amdgcn_s_barrier(); FENCE; } while (0)
#define VM8 0x0F78
#define VM0 0x0F70

__device__ __forceinline__ void gload_lds16(const void* g, void* l) {
  __builtin_amdgcn_global_load_lds(
      (const __attribute__((address_space(1))) u32*)g,
      (__attribute__((address_space(3))) u32*)l, 16, 0, 0);
}

__device__ __forceinline__ u32 pack2_bf16(float lo, float hi) {
  __hip_bfloat162 b2;
  b2.x = __float2bfloat16(lo);
  b2.y = __float2bfloat16(hi);
  return *reinterpret_cast<u32*>(&b2);
}

// truncating bf16x2 pack: one v_perm_b32 (lo = hi16(a), hi = hi16(b))
__device__ __forceinline__ u32 pk_trunc(float a, float b) {
  return __builtin_amdgcn_perm(__float_as_uint(b), __float_as_uint(a), 0x07060302u);
}

// relu(v) for v in (-1,1): med3(v,0,1) == clamp -> folds into v_sub_f32 clamp
__device__ __forceinline__ float reluc(float v) {
  return __builtin_amdgcn_fmed3f(v, 0.0f, 1.0f);
}

__device__ __forceinline__ float gelu_exact(float x) {
  return 0.5f * x * (1.0f + erff(x * 0.70710678118654752f));
}

// ---------------- prep1: per-feature min/max via monotone-key atomics + cw
__global__ void prep1_kernel(const float* __restrict__ x, u32* __restrict__ keys,
                             const float* __restrict__ depth_scores,
                             float* __restrict__ cw) {
  int t = threadIdx.x;
  int base = blockIdx.x * 256 + t;
  float mn = 1e30f, mx = -1e30f;
#pragma unroll
  for (int j = 0; j < 16; ++j) {
    float v = x[base + j * 16384];   // 16384 % 128 == 0 -> same feature i each iter
    mn = fminf(mn, v); mx = fmaxf(mx, v);
  }
  __shared__ float smn[256], smx[256];
  smn[t] = mn; smx[t] = mx;
  __syncthreads();
  if (t < 128) {
    mn = fminf(smn[t], smn[t + 128]);
    mx = fmaxf(smx[t], smx[t + 128]);
    int i = base & 127;  // == t
    atomicMax(&keys[i], 0x7FFFFFFFu - __float_as_uint(mn));
    atomicMax(&keys[128 + i], __float_as_uint(mx));
  }
  if (blockIdx.x == 0 && t == 0) {
    float m = -1e30f;
    for (int d0 = 0; d0 < DEPTH; ++d0) m = fmaxf(m, depth_scores[d0]);
    float e[DEPTH]; float sum = 0.f;
    for (int d0 = 0; d0 < DEPTH; ++d0) { e[d0] = expf(depth_scores[d0] - m); sum += e[d0]; }
    float cacc = 0.f; float cs[DEPTH];
    for (int d0 = DEPTH - 1; d0 >= 0; --d0) { cacc += e[d0] / sum; cs[d0] = cacc; }
    for (int d0 = 0; d0 < DEPTH; ++d0) cw[d0] = cs[d0];
  }
}

// ---------------- prep2: z_t[i][b] via LDS transpose (256B contiguous stores)
__global__ void prep2_kernel(const float* __restrict__ x, const u32* __restrict__ keys,
                             float* __restrict__ z_t) {
  __shared__ float lds[128 * 65];
  int t = threadIdx.x;
  int b0 = blockIdx.x * 64;
#pragma unroll
  for (int q = 0; q < 32; ++q) {
    int idx = q * 256 + t;              // [0, 8192)
    int b = idx >> 7, i = idx & 127;
    lds[i * 65 + b] = x[(size_t)(b0 + b) * IN_DIM + i];
  }
  __syncthreads();
#pragma unroll
  for (int q = 0; q < 32; ++q) {
    int idx = q * 256 + t;
    int ii = idx >> 6, bb = idx & 63;
    float mnv = __uint_as_float(0x7FFFFFFFu - keys[ii]);
    float mxv = __uint_as_float(keys[128 + ii]);
    float v = (lds[ii * 65 + bb] - mnv) * (1.0f / (mxv - mnv + 1e-6f));
    z_t[(size_t)ii * BATCH + b0 + bb] = v;
  }
}

// ---------------- fs fp32 [d,i,g,h] -> c_d*bf16, MFMA-frag-ordered fs2 ----------------
// DMA version (validated round 7): per ks-quarter, waves DMA 8 rows each via
// global_load_lds with XOR-pre-swizzled source; scale+pack in phase 2.
__global__ void convert_kernel(const float* __restrict__ fs,
                               const float* __restrict__ cw,
                               __hip_bfloat16* __restrict__ fs2) {
  __shared__ __align__(16) float lds[32 * 256];   // 32KB: one ks-quarter
  int slab = blockIdx.x;          // d*128 + i
  int t = threadIdx.x;
  int w = t >> 6, l = t & 63;
  float cd = cw[slab >> 7];
  const float* src = fs + (size_t)slab * (GRIDN * HID);
  char* dstb = (char*)fs2 + (size_t)slab * 65536;

  for (int ks = 0; ks < 4; ++ks) {
    const float* s0 = src + (size_t)ks * 32 * HID;
    // phase 1: wave w DMAs rows r = w*8..w*8+7 (g = ks*32 + r)
#pragma unroll
    for (int i = 0; i < 8; ++i) {
      int r = w * 8 + i;
      int mask = ((r >> 3) & 3) << 3;
      gload_lds16(s0 + (size_t)r * HID + ((l * 4) ^ mask),
                  (char*)lds + r * 1024);
    }
    WAITV(VM0);        // own DMA drained; barrier -> all waves' rows in
    BARR;
    // phase 2: emit the 1024 16B-slots of this ks (4 per thread)
#pragma unroll
    for (int it = 0; it < 4; ++it) {
      int task = t + it * 256;          // [0,1024)
      int nhalf = task >> 9;
      int q = task & 511;
      int tt = q >> 6, l4 = (q >> 4) & 3, l15 = q & 15;
      int h = nhalf * 128 + tt * 16 + l15;
      int msk = l4 << 3;                // == ((r>>3)&3)<<3 for r = l4*8+(0..7)
      int hx = h ^ msk;
      uint4 pk4;
      {
        float a0 = lds[(l4 * 8 + 0) * 256 + hx];
        float b0 = lds[(l4 * 8 + 1) * 256 + hx];
        float a1 = lds[(l4 * 8 + 2) * 256 + hx];
        float b1 = lds[(l4 * 8 + 3) * 256 + hx];
        float a2 = lds[(l4 * 8 + 4) * 256 + hx];
        float b2 = lds[(l4 * 8 + 5) * 256 + hx];
        float a3 = lds[(l4 * 8 + 6) * 256 + hx];
        float b3 = lds[(l4 * 8 + 7) * 256 + hx];
        pk4.x = pack2_bf16(cd * a0, cd * b0);
        pk4.y = pack2_bf16(cd * a1, cd * b1);
        pk4.z = pack2_bf16(cd * a2, cd * b2);
        pk4.w = pack2_bf16(cd * a3, cd * b3);
      }
      size_t off = (size_t)nhalf * 32768 + (size_t)ks * 8192 +
                   (size_t)tt * 1024 + l4 * 256 + l15 * 16;
      *(uint4*)(dstb + off) = pk4;
    }
    BARR;              // reads done before next quarter's DMA overwrites
  }
}

// ---------------- big GEMM: h_pre += relu(z-grids) @ (c_d*fs) ----------------
// SHARED-staging TRIPLE-buffered pipeline, ONE barrier per K-step — now at
// 3 blocks/CU occupancy: wave tile 64Mx64N (acc 64 regs, ~140 total -> 3
// waves/SIMD vs 2). Block = 4 waves 2M(wm)x2N(wn2) over a 128Mx128N tile;
// grid: 16 mtiles x 2 nhalves x 32 chunks = 1024 blocks, XCD-swizzled.
// Invariants vs round-5 kernel: chip MFMA count, LDS-read bytes, staging
// bytes/wave (2 gload_lds + 6 zg loads/step -> SAME vmcnt(8) ledger),
// atomic count (split-K=32). Cost: afgen duplicated across the 2 N-waves
// of a row pair (chip VALU for A-gen x2 — VALU far from saturated).
__launch_bounds__(256, 3)
__global__ void gemm_kernel(const float* __restrict__ z_t,
                            const float* __restrict__ grids,
                            const __hip_bfloat16* __restrict__ fs2,
                            float* __restrict__ h_pre) {
  __shared__ __align__(16) char lds[24576];   // 3 x 8KB shared triple buffer

  int bx = blockIdx.x;
  int xcd = bx & 7;
  int t6 = bx >> 3;                 // [0,128)
  int cg2 = t6 >> 5;                // [0,4)
  int jb2 = t6 & 31;                // [0,32): mtile(128) * nhalf
  int chunk = xcd + 8 * cg2;        // [0,32); same-XCD blocks share fs2 chunk
  int slab0 = chunk * 28;
  int mt = jb2 >> 1;                // [0,16) 128-row mtile
  int nh = jb2 & 1;                 // n-half of output (128 cols)

  int tid = threadIdx.x;
  int w = tid >> 6, l = tid & 63;
  int l15 = l & 15, l4 = l >> 4;
  int wm = w >> 1;                  // m-half within mtile
  int wn2 = w & 1;                  // 64-col quarter within nhalf
  int mbase = mt * 128 + wm * 64;   // wave: 64-row strip
  int nbase = nh * 128 + wn2 * 64;  // wave: 64-col strip

  floatx4 acc[4][4];
#pragma unroll
  for (int a = 0; a < 4; ++a)
#pragma unroll
    for (int b = 0; b < 4; ++b) acc[a][b] = (floatx4)0.f;

  // this wave's 2KB staging slice base (per-lane src; dest lane-offset is HW)
  const char* fsb = (const char*)fs2 + (size_t)slab0 * 65536 + (size_t)nh * 32768 +
                    (size_t)w * 2048 + (size_t)l * 16;

  // stage full step u (block: 8KB; this wave: 2KB = 2 x 1KB) -> buf[bufIdx]
  auto stage8 = [&](int u, int bufIdx) {
    const char* srcb = fsb + (size_t)(u >> 2) * 65536 + (size_t)(u & 3) * 8192;
    char* dst = lds + bufIdx * 8192 + w * 2048;
    gload_lds16(srcb, dst);
    gload_lds16(srcb + 1024, dst + 1024);
  };

  float4 zA, zB;                    // z regs, parity by step (even=A, odd=B)
  float4 g0A, g1A, g0B, g1B;
  auto zgload = [&](int s, float4& zv, float4& G0, float4& G1) {
    int slab = slab0 + (s >> 2);
    int iz = slab & 127;
    const float* zp = z_t + (size_t)iz * BATCH + mbase + l15;
    zv.x = zp[0]; zv.y = zp[16]; zv.z = zp[32]; zv.w = zp[48];
    const float* gp = grids + (size_t)slab * GRIDN + (s & 3) * 32 + l4 * 8;
    G0 = *(const float4*)gp;
    G1 = *(const float4*)(gp + 4);
  };

  short8 af[4];
  short8 bf[4];
  // wave reads its 64-col quarter: slots tt = wn2*4 .. wn2*4+3 (4KB of the 8)
  auto rdfrag4 = [&](int bufIdx) {
    const char* bp = lds + bufIdx * 8192 + wn2 * 4096 + l * 16;
#pragma unroll
    for (int j = 0; j < 4; ++j)
      bf[j] = *(const short8*)(bp + j * 1024);
  };
  // A fragments: relu(z - grid) via sub+clamp, truncating bf16 pack
  auto afgen = [&](const float4 zv, const float4 G0, const float4 G1) {
#pragma unroll
    for (int u = 0; u < 4; ++u) {
      float zu = (u == 0) ? zv.x : (u == 1) ? zv.y : (u == 2) ? zv.z : zv.w;
      union { uint4 q; short8 s8; } pk;
      pk.q.x = pk_trunc(reluc(zu - G0.x), reluc(zu - G0.y));
      pk.q.y = pk_trunc(reluc(zu - G0.z), reluc(zu - G0.w));
      pk.q.z = pk_trunc(reluc(zu - G1.x), reluc(zu - G1.y));
      pk.q.w = pk_trunc(reluc(zu - G1.z), reluc(zu - G1.w));
      af[u] = pk.s8;
    }
  };
  auto mfma16 = [&]() {
    __builtin_amdgcn_s_setprio(1);
#pragma unroll
    for (int u = 0; u < 4; ++u)
#pragma unroll
      for (int j = 0; j < 4; ++j)
        acc[u][j] = __builtin_amdgcn_mfma_f32_16x16x32_bf16(af[u], bf[j], acc[u][j], 0, 0, 0);
    __builtin_amdgcn_s_setprio(0);
  };

// full step: wait own slices+zg of step S -> barrier (all waves' slices in),
// stage S+2, ds_read frags, gen A (hides LDS latency), prefetch zg(S+2), MFMA.
#define STEP_FULL(S, BUF, STBUF, ZV, G0, G1)                                   \
  do {                                                                         \
    WAITV(VM8); BARR;                                                          \
    stage8((S) + 2, (STBUF)); FENCE;                                           \
    rdfrag4(BUF);                                                              \
    afgen(ZV, G0, G1);                                                         \
    zgload((S) + 2, ZV, G0, G1); FENCE;                                        \
    mfma16();                                                                  \
  } while (0)

  // prologue: queue = [St0:2, Zg0:6, St1:2, Zg1:6] = 16 in flight
  stage8(0, 0); FENCE;
  zgload(0, zA, g0A, g1A); FENCE;
  stage8(1, 1); FENCE;
  zgload(1, zB, g0B, g1B); FENCE;

  // main loop: steps 0..107, buf = s%3, zg parity = s%2; uniform vmcnt(8)
#pragma unroll 1
  for (int s0 = 0; s0 < 108; s0 += 6) {
    STEP_FULL(s0 + 0, 0, 2, zA, g0A, g1A);
    STEP_FULL(s0 + 1, 1, 0, zB, g0B, g1B);
    STEP_FULL(s0 + 2, 2, 1, zA, g0A, g1A);
    STEP_FULL(s0 + 3, 0, 2, zB, g0B, g1B);
    STEP_FULL(s0 + 4, 1, 0, zA, g0A, g1A);
    STEP_FULL(s0 + 5, 2, 1, zB, g0B, g1B);
  }

  // ---- tail ----
  STEP_FULL(108, 0, 2, zA, g0A, g1A);
  STEP_FULL(109, 1, 0, zB, g0B, g1B);
  WAITV(VM8); BARR;
  rdfrag4(2);
  afgen(zA, g0A, g1A);
  mfma16();
  WAITV(VM0); BARR;
  rdfrag4(0);
  afgen(zB, g0B, g1B);
  mfma16();

  // epilogue: atomic accumulate (C/D: col=l&15, row=(l>>4)*4+r)
  int row0 = mbase + l4 * 4;
  int col0 = nbase + l15;
#pragma unroll
  for (int u = 0; u < 4; ++u) {
#pragma unroll
    for (int j = 0; j < 4; ++j) {
      int col = col0 + j * 16;
#pragma unroll
      for (int r = 0; r < 4; ++r) {
        int row = row0 + u * 16 + r;
        atomicAdd(&h_pre[(size_t)row * HID + col], acc[u][j][r]);
      }
    }
  }
}

// ---------------- MLP layer: Y = act(X) @ W + b, col stats of Y ----------------
template <int FIRST>
__global__ void mlp_kernel(const float* __restrict__ Xin,
                           const float* __restrict__ statsIn,
                           const float* __restrict__ gamma,
                           const float* __restrict__ beta,
                           const float* __restrict__ W,
                           const float* __restrict__ bias,
                           float* __restrict__ Yout,
                           float* __restrict__ statsOut) {
  __shared__ float Xs[4][HID];
  int br = blockIdx.x, c = threadIdx.x;
  float mean = 0.f, rstd = 1.f, gm = 1.f, bt = 0.f;
  if (!FIRST) {
    float s1 = statsIn[c], s2 = statsIn[HID + c];
    mean = s1 * (1.0f / BATCH);
    float var = s2 * (1.0f / BATCH) - mean * mean;
    rstd = rsqrtf(var + 1e-5f);
    gm = gamma[c]; bt = beta[c];
  }
#pragma unroll
  for (int r = 0; r < 4; ++r) {
    float v = Xin[(size_t)(br * 4 + r) * HID + c];
    if (!FIRST) v = gelu_exact((v - mean) * rstd * gm + bt);
    Xs[r][c] = v;
  }
  __syncthreads();
  float acc[4] = {0, 0, 0, 0};
#pragma unroll 8
  for (int k = 0; k < HID; ++k) {
    float wv = W[(size_t)k * HID + c];
#pragma unroll
    for (int r = 0; r < 4; ++r) acc[r] += Xs[r][k] * wv;
  }
  float bb = bias[c];
  float s1 = 0.f, s2 = 0.f;
#pragma unroll
  for (int r = 0; r < 4; ++r) {
    float y = acc[r] + bb;
    Yout[(size_t)(br * 4 + r) * HID + c] = y;
    s1 += y; s2 += y * y;
  }
  atomicAdd(&statsOut[c], s1);
  atomicAdd(&statsOut[HID + c], s2);
}

// ---------------- final: out = gelu(bn(Y3)) @ W_out + b_out ----------------
__global__ void final_kernel(const float* __restrict__ Y3,
                             const float* __restrict__ statsIn,
                             const float* __restrict__ gamma,
                             const float* __restrict__ beta,
                             const float* __restrict__ W_out,
                             const float* __restrict__ b_out,
                             float* __restrict__ out) {
  int w = threadIdx.x >> 6, l = threadIdx.x & 63;
  int b = blockIdx.x * 4 + w;
  float4 y = *(const float4*)(Y3 + (size_t)b * HID + l * 4);
  float4 wv = *(const float4*)(W_out + l * 4);
  float r4[4] = {y.x, y.y, y.z, y.w};
  float w4[4] = {wv.x, wv.y, wv.z, wv.w};
  float s = 0.f;
  int c0 = l * 4;
#pragma unroll
  for (int q = 0; q < 4; ++q) {
    int c = c0 + q;
    float s1 = statsIn[c], s2 = statsIn[HID + c];
    float mean = s1 * (1.0f / BATCH);
    float var = s2 * (1.0f / BATCH) - mean * mean;
    float rstd = rsqrtf(var + 1e-5f);
    float v = gelu_exact((r4[q] - mean) * rstd * gamma[c] + beta[c]);
    s += v * w4[q];
  }
#pragma unroll
  for (int off = 32; off > 0; off >>= 1) s += __shfl_down(s, off);
  if (l == 0) out[b] = s + b_out[0];
}

extern "C" void kernel_launch(void* const* d_in, const int* in_sizes, int n_in,
                              void* d_out, int out_size, void* d_ws, size_t ws_size,
                              hipStream_t stream) {
  const float* x      = (const float*)d_in[0];
  const float* grids  = (const float*)d_in[1];
  const float* fs     = (const float*)d_in[2];
  const float* dscore = (const float*)d_in[3];
  const float* mlp_W  = (const float*)d_in[4];
  const float* mlp_b  = (const float*)d_in[5];
  const float* bn_g   = (const float*)d_in[6];
  const float* bn_b   = (const float*)d_in[7];
  const float* W_out  = (const float*)d_in[8];
  const float* b_out  = (const float*)d_in[9];
  float* out = (float*)d_out;

  char* ws = (char*)d_ws;
  __hip_bfloat16* fs2 = (__hip_bfloat16*)(ws + OFF_FST);
  float* z_t   = (float*)(ws + OFF_ZT);
  float* h_pre = (float*)(ws + OFF_HPRE);
  float* stats = (float*)(ws + OFF_STATS);
  u32*   keys  = (u32*)(ws + OFF_KEYS);
  float* cw    = (float*)(ws + OFF_CW);
  float* Y1    = (float*)(ws + OFF_Y1);
  float* Y2    = (float*)(ws + OFF_Y2);
  float* Y3    = (float*)(ws + OFF_Y3);

  // zero the atomic accumulators (h_pre + BN stats + minmax keys)
  hipMemsetAsync(h_pre, 0, SZ_HPRE + SZ_STATS + SZ_KEYS, stream);

  prep1_kernel<<<64, 256, 0, stream>>>(x, keys, dscore, cw);
  prep2_kernel<<<32, 256, 0, stream>>>(x, keys, z_t);
  convert_kernel<<<DEPTH * IN_DIM, 256, 0, stream>>>(fs, cw, fs2);
  gemm_kernel<<<1024, 256, 0, stream>>>(z_t, grids, fs2, h_pre);

  mlp_kernel<1><<<512, 256, 0, stream>>>(h_pre, nullptr, nullptr, nullptr,
                                         mlp_W, mlp_b, Y1, stats);
  mlp_kernel<0><<<512, 256, 0, stream>>>(Y1, stats, bn_g, bn_b,
                                         mlp_W + 65536, mlp_b + 256, Y2, stats + 512);
  mlp_kernel<0><<<512, 256, 0, stream>>>(Y2, stats + 512, bn_g + 256, bn_b + 256,
                                         mlp_W + 2 * 65536, mlp_b + 2 * 256, Y3, stats + 1024);
  final_kernel<<<512, 256, 0, stream>>>(Y3, stats + 1024, bn_g + 512, bn_b + 512,
                                        W_out, b_out, out);
}

// Round 9
// 425.352 us; speedup vs baseline: 1.0181x; 1.0181x over previous
//
#include <hip/hip_runtime.h>
#include <hip/hip_bf16.h>

#define BATCH 2048
#define IN_DIM 128
#define GRIDN 128
#define HID 256
#define DEPTH 7

typedef unsigned int u32;
typedef __attribute__((ext_vector_type(8))) short short8;
typedef __attribute__((ext_vector_type(4))) float floatx4;

// ---------------- ws layout (bytes) ----------------
// fs2: bf16, MFMA-frag-ordered: [slab:896][nhalf:2][ks:4][tt:8][l4:4][l15:16][g8:8]
#define OFF_FST   ((size_t)0)
#define SZ_FST    ((size_t)7*128*256*128*2)       // 58,720,256
#define OFF_ZT    (OFF_FST + SZ_FST)              // fp32 z_t [128][2048]
#define SZ_ZT     ((size_t)BATCH*IN_DIM*4)
#define OFF_HPRE  (OFF_ZT + SZ_ZT)                // fp32 h_pre [2048][256]
#define SZ_HPRE   ((size_t)BATCH*HID*4)
#define OFF_STATS (OFF_HPRE + SZ_HPRE)            // fp32 stats 3*[512]
#define SZ_STATS  ((size_t)3*2*HID*4)
#define OFF_KEYS  (OFF_STATS + SZ_STATS)          // u32 keys [256]
#define SZ_KEYS   ((size_t)256*4)
#define OFF_CW    (OFF_KEYS + SZ_KEYS)            // (unused now)
#define SZ_CW     ((size_t)32)
#define OFF_Y1    (OFF_CW + SZ_CW)
#define SZ_Y      ((size_t)BATCH*HID*4)
#define OFF_Y2    (OFF_Y1 + SZ_Y)
#define OFF_Y3    (OFF_Y2 + SZ_Y)

#define FENCE __asm__ volatile("" ::: "memory")
#define WAITV(c) do { __builtin_amdgcn_s_waitcnt(c); FENCE; } while (0)
#define BARR do { FENCE; __builtin_amdgcn_s_barrier(); FENCE; } while (0)
#define VM8 0x0F78
#define VM4 0x0F74
#define VM0 0x0F70

__device__ __forceinline__ void gload_lds16(const void* g, void* l) {
  __builtin_amdgcn_global_load_lds(
      (const __attribute__((address_space(1))) u32*)g,
      (__attribute__((address_space(3))) u32*)l, 16, 0, 0);
}

__device__ __forceinline__ u32 pack2_bf16(float lo, float hi) {
  __hip_bfloat162 b2;
  b2.x = __float2bfloat16(lo);
  b2.y = __float2bfloat16(hi);
  return *reinterpret_cast<u32*>(&b2);
}

// truncating bf16x2 pack: one v_perm_b32 (lo = hi16(a), hi = hi16(b))
__device__ __forceinline__ u32 pk_trunc(float a, float b) {
  return __builtin_amdgcn_perm(__float_as_uint(b), __float_as_uint(a), 0x07060302u);
}

// relu(v) for v in (-1,1): med3(v,0,1) == clamp -> folds into v_sub_f32 clamp
__device__ __forceinline__ float reluc(float v) {
  return __builtin_amdgcn_fmed3f(v, 0.0f, 1.0f);
}

__device__ __forceinline__ float gelu_exact(float x) {
  return 0.5f * x * (1.0f + erff(x * 0.70710678118654752f));
}

// ---------------- fused convert + prep1 (independent roles, one dispatch) ----
// Blocks [0,896): fs fp32 [d,i,g,h] -> cd*bf16 MFMA-frag-ordered fs2, with a
//   3x16KB triple-buffered DMA pipeline over 8 16-row phases: DMA(p+2) issued
//   at phase p; every wait is counted vmcnt(4) (queue = [dma(p):4,dma(p+1):4]),
//   one barrier per phase, no full drains. cd (depth softmax-cumsum) computed
//   locally from depth_scores (removes the prep1 -> convert dependency).
// Blocks [896,960): prep1 role — per-feature min/max monotone-key atomics.
__global__ void convert_prep1_kernel(const float* __restrict__ fs,
                                     const float* __restrict__ depth_scores,
                                     const float* __restrict__ x,
                                     u32* __restrict__ keys,
                                     __hip_bfloat16* __restrict__ fs2) {
  __shared__ __align__(16) float lds3[3 * 16 * 256];   // 48KB
  int bid = blockIdx.x;
  int t = threadIdx.x;

  if (bid >= DEPTH * IN_DIM) {
    // ---- prep1 role ----
    int pb = bid - DEPTH * IN_DIM;     // [0,64)
    int base = pb * 256 + t;
    float mn = 1e30f, mx = -1e30f;
#pragma unroll
    for (int j = 0; j < 16; ++j) {
      float v = x[base + j * 16384];   // same feature i each iter
      mn = fminf(mn, v); mx = fmaxf(mx, v);
    }
    float* smn = lds3; float* smx = lds3 + 256;
    smn[t] = mn; smx[t] = mx;
    __syncthreads();
    if (t < 128) {
      mn = fminf(smn[t], smn[t + 128]);
      mx = fmaxf(smx[t], smx[t + 128]);
      int i = base & 127;
      atomicMax(&keys[i], 0x7FFFFFFFu - __float_as_uint(mn));
      atomicMax(&keys[128 + i], __float_as_uint(mx));
    }
    return;
  }

  // ---- convert role ----
  int slab = bid;                      // d*128 + i
  int w = t >> 6, l = t & 63;
  int d = slab >> 7;
  // local softmax-cumsum: cd = sum_{i>=d} softmax(ds)[i]
  float m = -1e30f; float ds[DEPTH];
#pragma unroll
  for (int i = 0; i < DEPTH; ++i) { ds[i] = depth_scores[i]; m = fmaxf(m, ds[i]); }
  float sum = 0.f, tail = 0.f;
#pragma unroll
  for (int i = 0; i < DEPTH; ++i) {
    float e = expf(ds[i] - m);
    sum += e;
    if (i >= d) tail += e;
  }
  float cd = tail / sum;

  const float* src = fs + (size_t)slab * (GRIDN * HID);
  char* dstb = (char*)fs2 + (size_t)slab * 65536;

  // DMA phase p: global g-rows p*16 + (w*4+i) -> buf p%3 slot (w*4+i), with
  // XOR-pre-swizzled source col so lds[r][j] = fs_r[j ^ mask(r)]
  auto dmaPhase = [&](int p) {
    const float* s0 = src + (size_t)p * 16 * HID;
    char* bb = (char*)lds3 + (p % 3) * 16384;
#pragma unroll
    for (int i = 0; i < 4; ++i) {
      int sl = w * 4 + i;
      int r = p * 16 + sl;
      int mask = ((r >> 3) & 3) << 3;
      gload_lds16(s0 + (size_t)sl * HID + ((l * 4) ^ mask), bb + sl * 1024);
    }
  };
  // pack phase p (ks = p>>1, half hh = p&1): emit 512 16B-slots (2/thread)
  auto packPhase = [&](int p) {
    int ks = p >> 1, hh = p & 1;
    const float* bb = lds3 + (p % 3) * 4096;   // floats
#pragma unroll
    for (int it = 0; it < 2; ++it) {
      int task = t + it * 256;        // [0,512)
      int nhalf = task >> 8;
      int q = task & 255;
      int tt = q >> 5, l4h = (q >> 4) & 1, l15 = q & 15;
      int l4 = hh * 2 + l4h;
      int hgl = nhalf * 128 + tt * 16 + l15;
      int hx = hgl ^ (l4 << 3);       // undo source swizzle (mask(r)=(l4&3)<<3)
      const float* rp = bb + (l4h * 8) * 256 + hx;
      uint4 pk4;
      pk4.x = pack2_bf16(cd * rp[0 * 256], cd * rp[1 * 256]);
      pk4.y = pack2_bf16(cd * rp[2 * 256], cd * rp[3 * 256]);
      pk4.z = pack2_bf16(cd * rp[4 * 256], cd * rp[5 * 256]);
      pk4.w = pack2_bf16(cd * rp[6 * 256], cd * rp[7 * 256]);
      size_t off = (size_t)nhalf * 32768 + (size_t)ks * 8192 +
                   (size_t)tt * 1024 + (size_t)l4 * 256 + (size_t)l15 * 16;
      *(uint4*)(dstb + off) = pk4;
    }
  };

  dmaPhase(0); dmaPhase(1); FENCE;
#pragma unroll 1
  for (int p = 0; p < 6; ++p) {
    WAITV(VM4); BARR;                  // dma(p) in for all waves
    dmaPhase(p + 2); FENCE;            // buf (p+2)%3: last read phase p-1, safe
    packPhase(p);
  }
  WAITV(VM4); BARR; packPhase(6);
  WAITV(VM0); BARR; packPhase(7);
}

// ---------------- prep2: z_t[i][b] via LDS transpose (256B contiguous stores)
__global__ void prep2_kernel(const float* __restrict__ x, const u32* __restrict__ keys,
                             float* __restrict__ z_t) {
  __shared__ float lds[128 * 65];
  int t = threadIdx.x;
  int b0 = blockIdx.x * 64;
#pragma unroll
  for (int q = 0; q < 32; ++q) {
    int idx = q * 256 + t;              // [0, 8192)
    int b = idx >> 7, i = idx & 127;
    lds[i * 65 + b] = x[(size_t)(b0 + b) * IN_DIM + i];
  }
  __syncthreads();
#pragma unroll
  for (int q = 0; q < 32; ++q) {
    int idx = q * 256 + t;
    int ii = idx >> 6, bb = idx & 63;
    float mnv = __uint_as_float(0x7FFFFFFFu - keys[ii]);
    float mxv = __uint_as_float(keys[128 + ii]);
    float v = (lds[ii * 65 + bb] - mnv) * (1.0f / (mxv - mnv + 1e-6f));
    z_t[(size_t)ii * BATCH + b0 + bb] = v;
  }
}

// ---------------- big GEMM: h_pre += relu(z-grids) @ (c_d*fs) ----------------
// SHARED-staging TRIPLE-buffered pipeline, ONE barrier per K-step — round-7
// best config (128.9 us, MfmaUtil ~40): 512 blocks, 2/CU, wave 64Mx128N.
__launch_bounds__(256, 2)
__global__ void gemm_kernel(const float* __restrict__ z_t,
                            const float* __restrict__ grids,
                            const __hip_bfloat16* __restrict__ fs2,
                            float* __restrict__ h_pre) {
  __shared__ __align__(16) char lds[24576];   // 3 x 8KB shared triple buffer

  int bx = blockIdx.x;
  int xcd = bx & 7;
  int t6 = bx >> 3;                 // [0,64)
  int cg2 = t6 >> 4;                // [0,4)
  int jb2 = t6 & 15;                // [0,16): mtile(256) * nhalf
  int chunk = xcd + 8 * cg2;        // [0,32); same-XCD blocks share fs2 chunk
  int slab0 = chunk * 28;
  int mt = jb2 >> 1;                // [0,8) 256-row mtile
  int nh = jb2 & 1;                 // n-half of output

  int tid = threadIdx.x;
  int w = tid >> 6, l = tid & 63;
  int l15 = l & 15, l4 = l >> 4;
  int mbase = mt * 256 + w * 64;    // each wave: distinct 64-row strip
  int nbase = nh * 128;

  floatx4 acc[4][8];
#pragma unroll
  for (int a = 0; a < 4; ++a)
#pragma unroll
    for (int b = 0; b < 8; ++b) acc[a][b] = (floatx4)0.f;

  // this wave's 2KB staging slice base (per-lane src; dest lane-offset is HW)
  const char* fsb = (const char*)fs2 + (size_t)slab0 * 65536 + (size_t)nh * 32768 +
                    (size_t)w * 2048 + (size_t)l * 16;

  // stage full step u (block: 8KB; this wave: 2KB = 2 x 1KB) -> buf[bufIdx]
  auto stage8 = [&](int u, int bufIdx) {
    const char* srcb = fsb + (size_t)(u >> 2) * 65536 + (size_t)(u & 3) * 8192;
    char* dst = lds + bufIdx * 8192 + w * 2048;
    gload_lds16(srcb, dst);
    gload_lds16(srcb + 1024, dst + 1024);
  };

  float4 zA, zB;                    // z regs, parity by step (even=A, odd=B)
  float4 g0A, g1A, g0B, g1B;
  auto zgload = [&](int s, float4& zv, float4& G0, float4& G1) {
    int slab = slab0 + (s >> 2);
    int iz = slab & 127;
    const float* zp = z_t + (size_t)iz * BATCH + mbase + l15;
    zv.x = zp[0]; zv.y = zp[16]; zv.z = zp[32]; zv.w = zp[48];
    const float* gp = grids + (size_t)slab * GRIDN + (s & 3) * 32 + l4 * 8;
    G0 = *(const float4*)gp;
    G1 = *(const float4*)(gp + 4);
  };

  short8 af[4];
  short8 bf[8];
  auto rdfrag8 = [&](int bufIdx) {
    const char* bp = lds + bufIdx * 8192 + l * 16;
#pragma unroll
    for (int tt = 0; tt < 8; ++tt)
      bf[tt] = *(const short8*)(bp + tt * 1024);
  };
  // A fragments: relu(z - grid) via sub+clamp, truncating bf16 pack
  auto afgen = [&](const float4 zv, const float4 G0, const float4 G1) {
#pragma unroll
    for (int u = 0; u < 4; ++u) {
      float zu = (u == 0) ? zv.x : (u == 1) ? zv.y : (u == 2) ? zv.z : zv.w;
      union { uint4 q; short8 s8; } pk;
      pk.q.x = pk_trunc(reluc(zu - G0.x), reluc(zu - G0.y));
      pk.q.y = pk_trunc(reluc(zu - G0.z), reluc(zu - G0.w));
      pk.q.z = pk_trunc(reluc(zu - G1.x), reluc(zu - G1.y));
      pk.q.w = pk_trunc(reluc(zu - G1.z), reluc(zu - G1.w));
      af[u] = pk.s8;
    }
  };
  auto mfma32 = [&]() {
    __builtin_amdgcn_s_setprio(1);
#pragma unroll
    for (int u = 0; u < 4; ++u)
#pragma unroll
      for (int tt = 0; tt < 8; ++tt)
        acc[u][tt] = __builtin_amdgcn_mfma_f32_16x16x32_bf16(af[u], bf[tt], acc[u][tt], 0, 0, 0);
    __builtin_amdgcn_s_setprio(0);
  };

// full step: wait own slices+zg of step S -> barrier (all waves' slices in),
// stage S+2, ds_read frags, gen A (hides LDS latency), prefetch zg(S+2), MFMA.
#define STEP_FULL(S, BUF, STBUF, ZV, G0, G1)                                   \
  do {                                                                         \
    WAITV(VM8); BARR;                                                          \
    stage8((S) + 2, (STBUF)); FENCE;                                           \
    rdfrag8(BUF);                                                              \
    afgen(ZV, G0, G1);                                                         \
    zgload((S) + 2, ZV, G0, G1); FENCE;                                        \
    mfma32();                                                                  \
  } while (0)

  // prologue: queue = [St0:2, Zg0:6, St1:2, Zg1:6] = 16 in flight
  stage8(0, 0); FENCE;
  zgload(0, zA, g0A, g1A); FENCE;
  stage8(1, 1); FENCE;
  zgload(1, zB, g0B, g1B); FENCE;

  // main loop: steps 0..107, buf = s%3, zg parity = s%2; uniform vmcnt(8)
#pragma unroll 1
  for (int s0 = 0; s0 < 108; s0 += 6) {
    STEP_FULL(s0 + 0, 0, 2, zA, g0A, g1A);
    STEP_FULL(s0 + 1, 1, 0, zB, g0B, g1B);
    STEP_FULL(s0 + 2, 2, 1, zA, g0A, g1A);
    STEP_FULL(s0 + 3, 0, 2, zB, g0B, g1B);
    STEP_FULL(s0 + 4, 1, 0, zA, g0A, g1A);
    STEP_FULL(s0 + 5, 2, 1, zB, g0B, g1B);
  }

  // ---- tail ----
  STEP_FULL(108, 0, 2, zA, g0A, g1A);
  STEP_FULL(109, 1, 0, zB, g0B, g1B);
  WAITV(VM8); BARR;
  rdfrag8(2);
  afgen(zA, g0A, g1A);
  mfma32();
  WAITV(VM0); BARR;
  rdfrag8(0);
  afgen(zB, g0B, g1B);
  mfma32();

  // epilogue: atomic accumulate (C/D: col=l&15, row=(l>>4)*4+r)
  int row0 = mbase + l4 * 4;
  int col0 = nbase + l15;
#pragma unroll
  for (int u = 0; u < 4; ++u) {
#pragma unroll
    for (int tt = 0; tt < 8; ++tt) {
      int col = col0 + tt * 16;
#pragma unroll
      for (int r = 0; r < 4; ++r) {
        int row = row0 + u * 16 + r;
        atomicAdd(&h_pre[(size_t)row * HID + col], acc[u][tt][r]);
      }
    }
  }
}

// ---------------- MLP layer: Y = act(X) @ W + b, col stats of Y ----------------
template <int FIRST>
__global__ void mlp_kernel(const float* __restrict__ Xin,
                           const float* __restrict__ statsIn,
                           const float* __restrict__ gamma,
                           const float* __restrict__ beta,
                           const float* __restrict__ W,
                           const float* __restrict__ bias,
                           float* __restrict__ Yout,
                           float* __restrict__ statsOut) {
  __shared__ float Xs[4][HID];
  int br = blockIdx.x, c = threadIdx.x;
  float mean = 0.f, rstd = 1.f, gm = 1.f, bt = 0.f;
  if (!FIRST) {
    float s1 = statsIn[c], s2 = statsIn[HID + c];
    mean = s1 * (1.0f / BATCH);
    float var = s2 * (1.0f / BATCH) - mean * mean;
    rstd = rsqrtf(var + 1e-5f);
    gm = gamma[c]; bt = beta[c];
  }
#pragma unroll
  for (int r = 0; r < 4; ++r) {
    float v = Xin[(size_t)(br * 4 + r) * HID + c];
    if (!FIRST) v = gelu_exact((v - mean) * rstd * gm + bt);
    Xs[r][c] = v;
  }
  __syncthreads();
  float acc[4] = {0, 0, 0, 0};
#pragma unroll 8
  for (int k = 0; k < HID; ++k) {
    float wv = W[(size_t)k * HID + c];
#pragma unroll
    for (int r = 0; r < 4; ++r) acc[r] += Xs[r][k] * wv;
  }
  float bb = bias[c];
  float s1 = 0.f, s2 = 0.f;
#pragma unroll
  for (int r = 0; r < 4; ++r) {
    float y = acc[r] + bb;
    Yout[(size_t)(br * 4 + r) * HID + c] = y;
    s1 += y; s2 += y * y;
  }
  atomicAdd(&statsOut[c], s1);
  atomicAdd(&statsOut[HID + c], s2);
}

// ---------------- final: out = gelu(bn(Y3)) @ W_out + b_out ----------------
__global__ void final_kernel(const float* __restrict__ Y3,
                             const float* __restrict__ statsIn,
                             const float* __restrict__ gamma,
                             const float* __restrict__ beta,
                             const float* __restrict__ W_out,
                             const float* __restrict__ b_out,
                             float* __restrict__ out) {
  int w = threadIdx.x >> 6, l = threadIdx.x & 63;
  int b = blockIdx.x * 4 + w;
  float4 y = *(const float4*)(Y3 + (size_t)b * HID + l * 4);
  float4 wv = *(const float4*)(W_out + l * 4);
  float r4[4] = {y.x, y.y, y.z, y.w};
  float w4[4] = {wv.x, wv.y, wv.z, wv.w};
  float s = 0.f;
  int c0 = l * 4;
#pragma unroll
  for (int q = 0; q < 4; ++q) {
    int c = c0 + q;
    float s1 = statsIn[c], s2 = statsIn[HID + c];
    float mean = s1 * (1.0f / BATCH);
    float var = s2 * (1.0f / BATCH) - mean * mean;
    float rstd = rsqrtf(var + 1e-5f);
    float v = gelu_exact((r4[q] - mean) * rstd * gamma[c] + beta[c]);
    s += v * w4[q];
  }
#pragma unroll
  for (int off = 32; off > 0; off >>= 1) s += __shfl_down(s, off);
  if (l == 0) out[b] = s + b_out[0];
}

extern "C" void kernel_launch(void* const* d_in, const int* in_sizes, int n_in,
                              void* d_out, int out_size, void* d_ws, size_t ws_size,
                              hipStream_t stream) {
  const float* x      = (const float*)d_in[0];
  const float* grids  = (const float*)d_in[1];
  const float* fs     = (const float*)d_in[2];
  const float* dscore = (const float*)d_in[3];
  const float* mlp_W  = (const float*)d_in[4];
  const float* mlp_b  = (const float*)d_in[5];
  const float* bn_g   = (const float*)d_in[6];
  const float* bn_b   = (const float*)d_in[7];
  const float* W_out  = (const float*)d_in[8];
  const float* b_out  = (const float*)d_in[9];
  float* out = (float*)d_out;

  char* ws = (char*)d_ws;
  __hip_bfloat16* fs2 = (__hip_bfloat16*)(ws + OFF_FST);
  float* z_t   = (float*)(ws + OFF_ZT);
  float* h_pre = (float*)(ws + OFF_HPRE);
  float* stats = (float*)(ws + OFF_STATS);
  u32*   keys  = (u32*)(ws + OFF_KEYS);
  float* Y1    = (float*)(ws + OFF_Y1);
  float* Y2    = (float*)(ws + OFF_Y2);
  float* Y3    = (float*)(ws + OFF_Y3);

  // zero the atomic accumulators (h_pre + BN stats + minmax keys)
  hipMemsetAsync(h_pre, 0, SZ_HPRE + SZ_STATS + SZ_KEYS, stream);

  convert_prep1_kernel<<<DEPTH * IN_DIM + 64, 256, 0, stream>>>(fs, dscore, x,
                                                                keys, fs2);
  prep2_kernel<<<32, 256, 0, stream>>>(x, keys, z_t);
  gemm_kernel<<<512, 256, 0, stream>>>(z_t, grids, fs2, h_pre);

  mlp_kernel<1><<<512, 256, 0, stream>>>(h_pre, nullptr, nullptr, nullptr,
                                         mlp_W, mlp_b, Y1, stats);
  mlp_kernel<0><<<512, 256, 0, stream>>>(Y1, stats, bn_g, bn_b,
                                         mlp_W + 65536, mlp_b + 256, Y2, stats + 512);
  mlp_kernel<0><<<512, 256, 0, stream>>>(Y2, stats + 512, bn_g + 256, bn_b + 256,
                                         mlp_W + 2 * 65536, mlp_b + 2 * 256, Y3, stats + 1024);
  final_kernel<<<512, 256, 0, stream>>>(Y3, stats + 1024, bn_g + 512, bn_b + 512,
                                        W_out, b_out, out);
}

// Round 10
// 420.793 us; speedup vs baseline: 1.0292x; 1.0108x over previous
//
#include <hip/hip_runtime.h>
#include <hip/hip_bf16.h>

#define BATCH 2048
#define IN_DIM 128
#define GRIDN 128
#define HID 256
#define DEPTH 7

typedef unsigned int u32;
typedef __attribute__((ext_vector_type(8))) short short8;
typedef __attribute__((ext_vector_type(4))) float floatx4;

// ---------------- ws layout (bytes) ----------------
// fs2: bf16, MFMA-frag-ordered: [slab:896][nhalf:2][ks:4][tt:8][l4:4][l15:16][g8:8]
#define OFF_FST   ((size_t)0)
#define SZ_FST    ((size_t)7*128*256*128*2)       // 58,720,256
#define OFF_ZT    (OFF_FST + SZ_FST)              // fp32 z_t [128][2048]
#define SZ_ZT     ((size_t)BATCH*IN_DIM*4)
#define OFF_HPRE  (OFF_ZT + SZ_ZT)                // fp32 h_pre [2048][256]
#define SZ_HPRE   ((size_t)BATCH*HID*4)
#define OFF_STATS (OFF_HPRE + SZ_HPRE)            // fp32 stats 3*[512]
#define SZ_STATS  ((size_t)3*2*HID*4)
#define OFF_KEYS  (OFF_STATS + SZ_STATS)          // u32 keys [256]
#define SZ_KEYS   ((size_t)256*4)
#define OFF_CW    (OFF_KEYS + SZ_KEYS)            // (unused now)
#define SZ_CW     ((size_t)32)
#define OFF_Y1    (OFF_CW + SZ_CW)
#define SZ_Y      ((size_t)BATCH*HID*4)
#define OFF_Y2    (OFF_Y1 + SZ_Y)
#define OFF_Y3    (OFF_Y2 + SZ_Y)

#define FENCE __asm__ volatile("" ::: "memory")
#define WAITV(c) do { __builtin_amdgcn_s_waitcnt(c); FENCE; } while (0)
#define BARR do { FENCE; __builtin_amdgcn_s_barrier(); FENCE; } while (0)
#define VM8 0x0F78
#define VM4 0x0F74
#define VM0 0x0F70

__device__ __forceinline__ void gload_lds16(const void* g, void* l) {
  __builtin_amdgcn_global_load_lds(
      (const __attribute__((address_space(1))) u32*)g,
      (__attribute__((address_space(3))) u32*)l, 16, 0, 0);
}

__device__ __forceinline__ u32 pack2_bf16(float lo, float hi) {
  __hip_bfloat162 b2;
  b2.x = __float2bfloat16(lo);
  b2.y = __float2bfloat16(hi);
  return *reinterpret_cast<u32*>(&b2);
}

// truncating bf16x2 pack: one v_perm_b32 (lo = hi16(a), hi = hi16(b))
__device__ __forceinline__ u32 pk_trunc(float a, float b) {
  return __builtin_amdgcn_perm(__float_as_uint(b), __float_as_uint(a), 0x07060302u);
}

// relu(v) for v in (-1,1): med3(v,0,1) == clamp -> folds into v_sub_f32 clamp
__device__ __forceinline__ float reluc(float v) {
  return __builtin_amdgcn_fmed3f(v, 0.0f, 1.0f);
}

__device__ __forceinline__ float gelu_exact(float x) {
  return 0.5f * x * (1.0f + erff(x * 0.70710678118654752f));
}

// ---------------- fused convert + prep1 (independent roles, one dispatch) ----
// Blocks [0,896): fs fp32 [d,i,g,h] -> cd*bf16 MFMA-frag-ordered fs2, with a
//   3x16KB triple-buffered DMA pipeline over 8 16-row phases (validated r9).
// Blocks [896,960): prep1 role — per-feature min/max monotone-key atomics.
__global__ void convert_prep1_kernel(const float* __restrict__ fs,
                                     const float* __restrict__ depth_scores,
                                     const float* __restrict__ x,
                                     u32* __restrict__ keys,
                                     __hip_bfloat16* __restrict__ fs2) {
  __shared__ __align__(16) float lds3[3 * 16 * 256];   // 48KB
  int bid = blockIdx.x;
  int t = threadIdx.x;

  if (bid >= DEPTH * IN_DIM) {
    // ---- prep1 role ----
    int pb = bid - DEPTH * IN_DIM;     // [0,64)
    int base = pb * 256 + t;
    float mn = 1e30f, mx = -1e30f;
#pragma unroll
    for (int j = 0; j < 16; ++j) {
      float v = x[base + j * 16384];   // same feature i each iter
      mn = fminf(mn, v); mx = fmaxf(mx, v);
    }
    float* smn = lds3; float* smx = lds3 + 256;
    smn[t] = mn; smx[t] = mx;
    __syncthreads();
    if (t < 128) {
      mn = fminf(smn[t], smn[t + 128]);
      mx = fmaxf(smx[t], smx[t + 128]);
      int i = base & 127;
      atomicMax(&keys[i], 0x7FFFFFFFu - __float_as_uint(mn));
      atomicMax(&keys[128 + i], __float_as_uint(mx));
    }
    return;
  }

  // ---- convert role ----
  int slab = bid;                      // d*128 + i
  int w = t >> 6, l = t & 63;
  int d = slab >> 7;
  // local softmax-cumsum: cd = sum_{i>=d} softmax(ds)[i]
  float m = -1e30f; float ds[DEPTH];
#pragma unroll
  for (int i = 0; i < DEPTH; ++i) { ds[i] = depth_scores[i]; m = fmaxf(m, ds[i]); }
  float sum = 0.f, tail = 0.f;
#pragma unroll
  for (int i = 0; i < DEPTH; ++i) {
    float e = expf(ds[i] - m);
    sum += e;
    if (i >= d) tail += e;
  }
  float cd = tail / sum;

  const float* src = fs + (size_t)slab * (GRIDN * HID);
  char* dstb = (char*)fs2 + (size_t)slab * 65536;

  // DMA phase p: global g-rows p*16 + (w*4+i) -> buf p%3 slot (w*4+i), with
  // XOR-pre-swizzled source col so lds[r][j] = fs_r[j ^ mask(r)]
  auto dmaPhase = [&](int p) {
    const float* s0 = src + (size_t)p * 16 * HID;
    char* bb = (char*)lds3 + (p % 3) * 16384;
#pragma unroll
    for (int i = 0; i < 4; ++i) {
      int sl = w * 4 + i;
      int r = p * 16 + sl;
      int mask = ((r >> 3) & 3) << 3;
      gload_lds16(s0 + (size_t)sl * HID + ((l * 4) ^ mask), bb + sl * 1024);
    }
  };
  // pack phase p (ks = p>>1, half hh = p&1): emit 512 16B-slots (2/thread)
  auto packPhase = [&](int p) {
    int ks = p >> 1, hh = p & 1;
    const float* bb = lds3 + (p % 3) * 4096;   // floats
#pragma unroll
    for (int it = 0; it < 2; ++it) {
      int task = t + it * 256;        // [0,512)
      int nhalf = task >> 8;
      int q = task & 255;
      int tt = q >> 5, l4h = (q >> 4) & 1, l15 = q & 15;
      int l4 = hh * 2 + l4h;
      int hgl = nhalf * 128 + tt * 16 + l15;
      int hx = hgl ^ (l4 << 3);       // undo source swizzle (mask(r)=(l4&3)<<3)
      const float* rp = bb + (l4h * 8) * 256 + hx;
      uint4 pk4;
      pk4.x = pack2_bf16(cd * rp[0 * 256], cd * rp[1 * 256]);
      pk4.y = pack2_bf16(cd * rp[2 * 256], cd * rp[3 * 256]);
      pk4.z = pack2_bf16(cd * rp[4 * 256], cd * rp[5 * 256]);
      pk4.w = pack2_bf16(cd * rp[6 * 256], cd * rp[7 * 256]);
      size_t off = (size_t)nhalf * 32768 + (size_t)ks * 8192 +
                   (size_t)tt * 1024 + (size_t)l4 * 256 + (size_t)l15 * 16;
      *(uint4*)(dstb + off) = pk4;
    }
  };

  dmaPhase(0); dmaPhase(1); FENCE;
#pragma unroll 1
  for (int p = 0; p < 6; ++p) {
    WAITV(VM4); BARR;                  // dma(p) in for all waves
    dmaPhase(p + 2); FENCE;            // buf (p+2)%3: last read phase p-1, safe
    packPhase(p);
  }
  WAITV(VM4); BARR; packPhase(6);
  WAITV(VM0); BARR; packPhase(7);
}

// ---------------- prep2: z_t[i][b] via LDS transpose (256B contiguous stores)
__global__ void prep2_kernel(const float* __restrict__ x, const u32* __restrict__ keys,
                             float* __restrict__ z_t) {
  __shared__ float lds[128 * 65];
  int t = threadIdx.x;
  int b0 = blockIdx.x * 64;
#pragma unroll
  for (int q = 0; q < 32; ++q) {
    int idx = q * 256 + t;              // [0, 8192)
    int b = idx >> 7, i = idx & 127;
    lds[i * 65 + b] = x[(size_t)(b0 + b) * IN_DIM + i];
  }
  __syncthreads();
#pragma unroll
  for (int q = 0; q < 32; ++q) {
    int idx = q * 256 + t;
    int ii = idx >> 6, bb = idx & 63;
    float mnv = __uint_as_float(0x7FFFFFFFu - keys[ii]);
    float mxv = __uint_as_float(keys[128 + ii]);
    float v = (lds[ii * 65 + bb] - mnv) * (1.0f / (mxv - mnv + 1e-6f));
    z_t[(size_t)ii * BATCH + b0 + bb] = v;
  }
}

// ---------------- big GEMM: h_pre += relu(z-grids) @ (c_d*fs) ----------------
// SHARED-staging TRIPLE-buffered pipeline, ONE barrier per K-step — round-7
// best config (128.9 us, MfmaUtil ~40): 512 blocks, 2/CU, wave 64Mx128N.
__launch_bounds__(256, 2)
__global__ void gemm_kernel(const float* __restrict__ z_t,
                            const float* __restrict__ grids,
                            const __hip_bfloat16* __restrict__ fs2,
                            float* __restrict__ h_pre) {
  __shared__ __align__(16) char lds[24576];   // 3 x 8KB shared triple buffer

  int bx = blockIdx.x;
  int xcd = bx & 7;
  int t6 = bx >> 3;                 // [0,64)
  int cg2 = t6 >> 4;                // [0,4)
  int jb2 = t6 & 15;                // [0,16): mtile(256) * nhalf
  int chunk = xcd + 8 * cg2;        // [0,32); same-XCD blocks share fs2 chunk
  int slab0 = chunk * 28;
  int mt = jb2 >> 1;                // [0,8) 256-row mtile
  int nh = jb2 & 1;                 // n-half of output

  int tid = threadIdx.x;
  int w = tid >> 6, l = tid & 63;
  int l15 = l & 15, l4 = l >> 4;
  int mbase = mt * 256 + w * 64;    // each wave: distinct 64-row strip
  int nbase = nh * 128;

  floatx4 acc[4][8];
#pragma unroll
  for (int a = 0; a < 4; ++a)
#pragma unroll
    for (int b = 0; b < 8; ++b) acc[a][b] = (floatx4)0.f;

  // this wave's 2KB staging slice base (per-lane src; dest lane-offset is HW)
  const char* fsb = (const char*)fs2 + (size_t)slab0 * 65536 + (size_t)nh * 32768 +
                    (size_t)w * 2048 + (size_t)l * 16;

  // stage full step u (block: 8KB; this wave: 2KB = 2 x 1KB) -> buf[bufIdx]
  auto stage8 = [&](int u, int bufIdx) {
    const char* srcb = fsb + (size_t)(u >> 2) * 65536 + (size_t)(u & 3) * 8192;
    char* dst = lds + bufIdx * 8192 + w * 2048;
    gload_lds16(srcb, dst);
    gload_lds16(srcb + 1024, dst + 1024);
  };

  float4 zA, zB;                    // z regs, parity by step (even=A, odd=B)
  float4 g0A, g1A, g0B, g1B;
  auto zgload = [&](int s, float4& zv, float4& G0, float4& G1) {
    int slab = slab0 + (s >> 2);
    int iz = slab & 127;
    const float* zp = z_t + (size_t)iz * BATCH + mbase + l15;
    zv.x = zp[0]; zv.y = zp[16]; zv.z = zp[32]; zv.w = zp[48];
    const float* gp = grids + (size_t)slab * GRIDN + (s & 3) * 32 + l4 * 8;
    G0 = *(const float4*)gp;
    G1 = *(const float4*)(gp + 4);
  };

  short8 af[4];
  short8 bf[8];
  auto rdfrag8 = [&](int bufIdx) {
    const char* bp = lds + bufIdx * 8192 + l * 16;
#pragma unroll
    for (int tt = 0; tt < 8; ++tt)
      bf[tt] = *(const short8*)(bp + tt * 1024);
  };
  // A fragments: relu(z - grid) via sub+clamp, truncating bf16 pack
  auto afgen = [&](const float4 zv, const float4 G0, const float4 G1) {
#pragma unroll
    for (int u = 0; u < 4; ++u) {
      float zu = (u == 0) ? zv.x : (u == 1) ? zv.y : (u == 2) ? zv.z : zv.w;
      union { uint4 q; short8 s8; } pk;
      pk.q.x = pk_trunc(reluc(zu - G0.x), reluc(zu - G0.y));
      pk.q.y = pk_trunc(reluc(zu - G0.z), reluc(zu - G0.w));
      pk.q.z = pk_trunc(reluc(zu - G1.x), reluc(zu - G1.y));
      pk.q.w = pk_trunc(reluc(zu - G1.z), reluc(zu - G1.w));
      af[u] = pk.s8;
    }
  };
  auto mfma32 = [&]() {
    __builtin_amdgcn_s_setprio(1);
#pragma unroll
    for (int u = 0; u < 4; ++u)
#pragma unroll
      for (int tt = 0; tt < 8; ++tt)
        acc[u][tt] = __builtin_amdgcn_mfma_f32_16x16x32_bf16(af[u], bf[tt], acc[u][tt], 0, 0, 0);
    __builtin_amdgcn_s_setprio(0);
  };

// full step: wait own slices+zg of step S -> barrier (all waves' slices in),
// stage S+2, ds_read frags, gen A (hides LDS latency), prefetch zg(S+2), MFMA.
#define STEP_FULL(S, BUF, STBUF, ZV, G0, G1)                                   \
  do {                                                                         \
    WAITV(VM8); BARR;                                                          \
    stage8((S) + 2, (STBUF)); FENCE;                                           \
    rdfrag8(BUF);                                                              \
    afgen(ZV, G0, G1);                                                         \
    zgload((S) + 2, ZV, G0, G1); FENCE;                                        \
    mfma32();                                                                  \
  } while (0)

  // prologue: queue = [St0:2, Zg0:6, St1:2, Zg1:6] = 16 in flight
  stage8(0, 0); FENCE;
  zgload(0, zA, g0A, g1A); FENCE;
  stage8(1, 1); FENCE;
  zgload(1, zB, g0B, g1B); FENCE;

  // main loop: steps 0..107, buf = s%3, zg parity = s%2; uniform vmcnt(8)
#pragma unroll 1
  for (int s0 = 0; s0 < 108; s0 += 6) {
    STEP_FULL(s0 + 0, 0, 2, zA, g0A, g1A);
    STEP_FULL(s0 + 1, 1, 0, zB, g0B, g1B);
    STEP_FULL(s0 + 2, 2, 1, zA, g0A, g1A);
    STEP_FULL(s0 + 3, 0, 2, zB, g0B, g1B);
    STEP_FULL(s0 + 4, 1, 0, zA, g0A, g1A);
    STEP_FULL(s0 + 5, 2, 1, zB, g0B, g1B);
  }

  // ---- tail ----
  STEP_FULL(108, 0, 2, zA, g0A, g1A);
  STEP_FULL(109, 1, 0, zB, g0B, g1B);
  WAITV(VM8); BARR;
  rdfrag8(2);
  afgen(zA, g0A, g1A);
  mfma32();
  WAITV(VM0); BARR;
  rdfrag8(0);
  afgen(zB, g0B, g1B);
  mfma32();

  // epilogue: atomic accumulate (C/D: col=l&15, row=(l>>4)*4+r)
  int row0 = mbase + l4 * 4;
  int col0 = nbase + l15;
#pragma unroll
  for (int u = 0; u < 4; ++u) {
#pragma unroll
    for (int tt = 0; tt < 8; ++tt) {
      int col = col0 + tt * 16;
#pragma unroll
      for (int r = 0; r < 4; ++r) {
        int row = row0 + u * 16 + r;
        atomicAdd(&h_pre[(size_t)row * HID + col], acc[u][tt][r]);
      }
    }
  }
}

// ---------------- MLP layer: Y = act(X) @ W + b, col stats of Y ----------------
// W staged in LDS via gload_lds double-buffer (8 tiles of 32 rows x 256 cols,
// 32KB each): kills the 256-deep serial chain of L2-latency-exposed scalar W
// loads. Summation order identical to the scalar version (same k order) ->
// bit-identical results. Ledger: stage(t+1) issued at iter-t top; wait vm8
// retires tile t (tile t+1's 8 loads remain); barrier-compute-barrier protects
// the double buffer.
template <int FIRST>
__launch_bounds__(256, 2)
__global__ void mlp_kernel(const float* __restrict__ Xin,
                           const float* __restrict__ statsIn,
                           const float* __restrict__ gamma,
                           const float* __restrict__ beta,
                           const float* __restrict__ W,
                           const float* __restrict__ bias,
                           float* __restrict__ Yout,
                           float* __restrict__ statsOut) {
  __shared__ float Xs[4][HID];                       // 4 KB
  __shared__ __align__(16) float Wl[2][32][HID];     // 64 KB double buffer
  int br = blockIdx.x, c = threadIdx.x;
  int w = c >> 6, l = c & 63;

  // stage W tile t (rows t*32..t*32+31); wave w stages rows w*8..w*8+7
  auto stageW = [&](int t, int buf) {
    const float* src = W + ((size_t)t * 32 + w * 8) * HID + l * 4;
#pragma unroll
    for (int i = 0; i < 8; ++i)
      gload_lds16(src + (size_t)i * HID, &Wl[buf][w * 8 + i][0]);
  };

  stageW(0, 0); FENCE;                // overlap HBM/L2 latency with BN+gelu

  float mean = 0.f, rstd = 1.f, gm = 1.f, bt = 0.f;
  if (!FIRST) {
    float s1 = statsIn[c], s2 = statsIn[HID + c];
    mean = s1 * (1.0f / BATCH);
    float var = s2 * (1.0f / BATCH) - mean * mean;
    rstd = rsqrtf(var + 1e-5f);
    gm = gamma[c]; bt = beta[c];
  }
#pragma unroll
  for (int r = 0; r < 4; ++r) {
    float v = Xin[(size_t)(br * 4 + r) * HID + c];
    if (!FIRST) v = gelu_exact((v - mean) * rstd * gm + bt);
    Xs[r][c] = v;
  }
  __syncthreads();

  float acc[4] = {0.f, 0.f, 0.f, 0.f};
#pragma unroll 1
  for (int t = 0; t < 8; ++t) {
    if (t < 7) { stageW(t + 1, (t + 1) & 1); FENCE; }
    if (t < 7) { WAITV(VM8); } else { WAITV(VM0); }
    BARR;                              // tile t in for all waves
    const float* wt = &Wl[t & 1][0][0];
    int kb = t * 32;
#pragma unroll 8
    for (int kk = 0; kk < 32; ++kk) {
      float wv = wt[kk * HID + c];
#pragma unroll
      for (int r = 0; r < 4; ++r) acc[r] += Xs[r][kb + kk] * wv;
    }
    BARR;                              // reads done before stage(t+2) overwrites
  }

  float bb = bias[c];
  float s1 = 0.f, s2 = 0.f;
#pragma unroll
  for (int r = 0; r < 4; ++r) {
    float y = acc[r] + bb;
    Yout[(size_t)(br * 4 + r) * HID + c] = y;
    s1 += y; s2 += y * y;
  }
  atomicAdd(&statsOut[c], s1);
  atomicAdd(&statsOut[HID + c], s2);
}

// ---------------- final: out = gelu(bn(Y3)) @ W_out + b_out ----------------
__global__ void final_kernel(const float* __restrict__ Y3,
                             const float* __restrict__ statsIn,
                             const float* __restrict__ gamma,
                             const float* __restrict__ beta,
                             const float* __restrict__ W_out,
                             const float* __restrict__ b_out,
                             float* __restrict__ out) {
  int w = threadIdx.x >> 6, l = threadIdx.x & 63;
  int b = blockIdx.x * 4 + w;
  float4 y = *(const float4*)(Y3 + (size_t)b * HID + l * 4);
  float4 wv = *(const float4*)(W_out + l * 4);
  float r4[4] = {y.x, y.y, y.z, y.w};
  float w4[4] = {wv.x, wv.y, wv.z, wv.w};
  float s = 0.f;
  int c0 = l * 4;
#pragma unroll
  for (int q = 0; q < 4; ++q) {
    int c = c0 + q;
    float s1 = statsIn[c], s2 = statsIn[HID + c];
    float mean = s1 * (1.0f / BATCH);
    float var = s2 * (1.0f / BATCH) - mean * mean;
    float rstd = rsqrtf(var + 1e-5f);
    float v = gelu_exact((r4[q] - mean) * rstd * gamma[c] + beta[c]);
    s += v * w4[q];
  }
#pragma unroll
  for (int off = 32; off > 0; off >>= 1) s += __shfl_down(s, off);
  if (l == 0) out[b] = s + b_out[0];
}

extern "C" void kernel_launch(void* const* d_in, const int* in_sizes, int n_in,
                              void* d_out, int out_size, void* d_ws, size_t ws_size,
                              hipStream_t stream) {
  const float* x      = (const float*)d_in[0];
  const float* grids  = (const float*)d_in[1];
  const float* fs     = (const float*)d_in[2];
  const float* dscore = (const float*)d_in[3];
  const float* mlp_W  = (const float*)d_in[4];
  const float* mlp_b  = (const float*)d_in[5];
  const float* bn_g   = (const float*)d_in[6];
  const float* bn_b   = (const float*)d_in[7];
  const float* W_out  = (const float*)d_in[8];
  const float* b_out  = (const float*)d_in[9];
  float* out = (float*)d_out;

  char* ws = (char*)d_ws;
  __hip_bfloat16* fs2 = (__hip_bfloat16*)(ws + OFF_FST);
  float* z_t   = (float*)(ws + OFF_ZT);
  float* h_pre = (float*)(ws + OFF_HPRE);
  float* stats = (float*)(ws + OFF_STATS);
  u32*   keys  = (u32*)(ws + OFF_KEYS);
  float* Y1    = (float*)(ws + OFF_Y1);
  float* Y2    = (float*)(ws + OFF_Y2);
  float* Y3    = (float*)(ws + OFF_Y3);

  // zero the atomic accumulators (h_pre + BN stats + minmax keys)
  hipMemsetAsync(h_pre, 0, SZ_HPRE + SZ_STATS + SZ_KEYS, stream);

  convert_prep1_kernel<<<DEPTH * IN_DIM + 64, 256, 0, stream>>>(fs, dscore, x,
                                                                keys, fs2);
  prep2_kernel<<<32, 256, 0, stream>>>(x, keys, z_t);
  gemm_kernel<<<512, 256, 0, stream>>>(z_t, grids, fs2, h_pre);

  mlp_kernel<1><<<512, 256, 0, stream>>>(h_pre, nullptr, nullptr, nullptr,
                                         mlp_W, mlp_b, Y1, stats);
  mlp_kernel<0><<<512, 256, 0, stream>>>(Y1, stats, bn_g, bn_b,
                                         mlp_W + 65536, mlp_b + 256, Y2, stats + 512);
  mlp_kernel<0><<<512, 256, 0, stream>>>(Y2, stats + 512, bn_g + 256, bn_b + 256,
                                         mlp_W + 2 * 65536, mlp_b + 2 * 256, Y3, stats + 1024);
  final_kernel<<<512, 256, 0, stream>>>(Y3, stats + 1024, bn_g + 512, bn_b + 512,
                                        W_out, b_out, out);
}